// Round 5
// baseline (281.267 us; speedup 1.0000x reference)
//
#include <hip/hip_runtime.h>
#include <hip/hip_bf16.h>
#include <math.h>
#include <stdint.h>

#define BB 4
#define TT 1024
#define EE 1024
#define HH 16
#define SS 64

typedef unsigned short ushort_t;
typedef __attribute__((ext_vector_type(8))) short bf16x8;
typedef __attribute__((ext_vector_type(8))) unsigned short u16x8;
typedef __attribute__((ext_vector_type(4))) unsigned short u16x4;
typedef __attribute__((ext_vector_type(4))) float f32x4;

__device__ __forceinline__ float b2f(ushort_t u) {
    union { float f; uint32_t i; } c;
    c.i = ((uint32_t)u) << 16;
    return c.f;
}
__device__ __forceinline__ ushort_t f2b(float f) {
    __hip_bfloat16 h = __float2bfloat16(f);
    return *(ushort_t*)&h;
}

// ---------------------------------------------------------------------------
// Kernel 0: fused fp32 -> bf16 converter, 4 elems/thread (Er then Wo)
// ---------------------------------------------------------------------------
__global__ __launch_bounds__(256) void cvt2_kernel(
    const float* __restrict__ a, ushort_t* __restrict__ da, int na,
    const float* __restrict__ b, ushort_t* __restrict__ db, int nb)
{
    const int i4 = (blockIdx.x * 256 + threadIdx.x) * 4;
    if (i4 < na) {
        const float4 xv = *(const float4*)&a[i4];
        u16x4 o4 = { f2b(xv.x), f2b(xv.y), f2b(xv.z), f2b(xv.w) };
        *(u16x4*)&da[i4] = o4;
    } else {
        const int j4 = i4 - na;
        if (j4 < nb) {
            const float4 xv = *(const float4*)&b[j4];
            u16x4 o4 = { f2b(xv.x), f2b(xv.y), f2b(xv.z), f2b(xv.w) };
            *(u16x4*)&db[j4] = o4;
        }
    }
}

// ---------------------------------------------------------------------------
// Kernel 1: MFMA q/k/v projection + fused vmean accumulation.
// R5 change: V is stored TRANSPOSED as vT[bh][d][t] (so attn can fetch PV
// B-fragments as single dwordx4 loads).  q/k unchanged.
// ---------------------------------------------------------------------------
__global__ __launch_bounds__(256) void qkv_kernel(
    const float* __restrict__ x, const float* __restrict__ Wq,
    const float* __restrict__ Wk, const float* __restrict__ Wv,
    ushort_t* __restrict__ q, ushort_t* __restrict__ k, ushort_t* __restrict__ vT,
    float* __restrict__ vmean)
{
    __shared__ __align__(16) ushort_t Xs[128][72];
    __shared__ __align__(16) ushort_t Wl[3][64][72];

    const int tid  = threadIdx.x;
    const int lane = tid & 63;
    const int w    = tid >> 6;
    const int m    = lane & 15;
    const int qd   = lane >> 4;
    const int n0   = blockIdx.x * 128;
    const int hh   = blockIdx.y;
    const int bb   = n0 >> 10;

#pragma unroll
    for (int l = 0; l < 8; l++) {
        const int idx = tid + 256 * l;
        const int row = idx >> 4;
        const int c4  = idx & 15;
        const float4 xv = *(const float4*)&x[(size_t)(n0 + row) * 1024 + hh * 64 + c4 * 4];
        u16x4 o4 = { f2b(xv.x), f2b(xv.y), f2b(xv.z), f2b(xv.w) };
        *(u16x4*)&Xs[row][c4 * 4] = o4;
    }
#pragma unroll
    for (int l = 0; l < 12; l++) {
        const int idx = tid + 256 * l;
        const int mo  = idx >> 10;
        const int r   = (idx >> 4) & 63;
        const int c4  = idx & 15;
        const float* W = (mo == 0) ? Wq : (mo == 1) ? Wk : Wv;
        const float4 wv = *(const float4*)&W[r * 64 + c4 * 4];
        u16x4 o4 = { f2b(wv.x), f2b(wv.y), f2b(wv.z), f2b(wv.w) };
        *(u16x4*)&Wl[mo][r][c4 * 4] = o4;
    }
    __syncthreads();

    f32x4 acc[2][3][4];
#pragma unroll
    for (int rt = 0; rt < 2; rt++)
#pragma unroll
        for (int mo = 0; mo < 3; mo++)
#pragma unroll
            for (int ct = 0; ct < 4; ct++) acc[rt][mo][ct] = {0.f, 0.f, 0.f, 0.f};

#pragma unroll
    for (int ks = 0; ks < 2; ks++) {
        bf16x8 af[2];
#pragma unroll
        for (int rt = 0; rt < 2; rt++)
            af[rt] = *(const bf16x8*)&Xs[32 * w + 16 * rt + m][ks * 32 + qd * 8];
#pragma unroll
        for (int mo = 0; mo < 3; mo++)
#pragma unroll
            for (int ct = 0; ct < 4; ct++) {
                bf16x8 bw = *(const bf16x8*)&Wl[mo][ct * 16 + m][ks * 32 + qd * 8];
#pragma unroll
                for (int rt = 0; rt < 2; rt++)
                    acc[rt][mo][ct] = __builtin_amdgcn_mfma_f32_16x16x32_bf16(
                        af[rt], bw, acc[rt][mo][ct], 0, 0, 0);
            }
    }

    const size_t obase = ((size_t)bb * HH + hh) * TT;
    const size_t vtbase = ((size_t)bb * HH + hh) * SS;
#pragma unroll
    for (int mo = 0; mo < 3; mo++) {
        const float sc = (mo == 1) ? 0.03125f : 1.0f;
#pragma unroll
        for (int rt = 0; rt < 2; rt++)
#pragma unroll
            for (int reg = 0; reg < 4; reg++) {
                const int t = (n0 & 1023) + 32 * w + 16 * rt + qd * 4 + reg;
#pragma unroll
                for (int ct = 0; ct < 4; ct++) {
                    const float val = acc[rt][mo][ct][reg] * sc;
                    if (mo == 0)
                        q[(obase + t) * SS + ct * 16 + m] = f2b(val);
                    else if (mo == 1)
                        k[(obase + t) * SS + ct * 16 + m] = f2b(val);
                    else
                        vT[(vtbase + ct * 16 + m) * TT + t] = f2b(val);
                }
            }
    }

#pragma unroll
    for (int ct = 0; ct < 4; ct++) {
        float s = 0.f;
#pragma unroll
        for (int rt = 0; rt < 2; rt++)
#pragma unroll
            for (int reg = 0; reg < 4; reg++) s += acc[rt][2][ct][reg];
        s += __shfl_xor(s, 16);
        s += __shfl_xor(s, 32);
        if (qd == 0)
            atomicAdd(&vmean[(bb * HH + hh) * SS + ct * 16 + m], s);
    }
}

// ---------------------------------------------------------------------------
// Kernel 3: MFMA bf16 flash attention.  R5: ZERO-STAGING / ZERO-BARRIER.
// Theory: R0-R4 are LDS-pipe throughput-bound (33 DS-pipe ops per wave-step
// incl. 12 ds_bpermute; per-CU pipe shared -> occupancy-invariant 59-61us).
// Fix: all MFMA operands (Q, K, Er, V) are fetched DIRECTLY from global
// (cache-resident: K/V 2MB/XCD, Er 1MB/XCD vs 4MB L2/XCD).  V comes from
// the transposed vT[d][t] layout so B-fragments are single dwordx4 loads.
// Er OOB rows (skew's pos_mask region) are zeroed via clamp+select, exactly
// reproducing the old Es-ring zero rows.  Ps stays (wave-private, in-order
// DS pipe per wave -> no barrier needed anywhere).  LDS 5KB, no syncthreads,
// 256 threads / 4 independent waves, 8 blocks/CU target.
// ---------------------------------------------------------------------------
__global__ __launch_bounds__(256, 8) void attn_kernel(
    const ushort_t* __restrict__ q, const ushort_t* __restrict__ k,
    const ushort_t* __restrict__ vT, const ushort_t* __restrict__ er,
    const int* __restrict__ mask, const float* __restrict__ vmean,
    ushort_t* __restrict__ attn)
{
    __shared__ __align__(16) ushort_t Ps[4][16][40];

    const int tid  = threadIdx.x;
    const int lane = tid & 63;
    const int w    = tid >> 6;
    const int m    = lane & 15;
    const int qd   = lane >> 4;
    const int bh   = blockIdx.x;
    const int bb   = bh >> 4;
    const int hh   = bh & 15;
    const int yt   = 15 - (int)blockIdx.y;   // LPT: longest blocks first
    const int i0   = yt * 64;
    const int steps = 2 * yt + 2;            // 32-wide j-steps

    const ushort_t* qb = q  + (size_t)bh * TT * SS;
    const ushort_t* kb = k  + (size_t)bh * TT * SS;
    const ushort_t* vb = vT + (size_t)bh * TT * SS;   // [d][t]
    const ushort_t* eb = er + (size_t)hh * TT * SS;
    const int l0 = 960 - i0;                 // >= 0 (i0 <= 960)

    // Q fragments direct from global (once per wave; verified R3/R4 pattern)
    bf16x8 aq[2];
#pragma unroll
    for (int ks = 0; ks < 2; ks++)
        aq[ks] = *(const bf16x8*)&qb[(size_t)(i0 + 16 * w + m) * SS + ks * 32 + qd * 8];

    f32x4 o[4];
#pragma unroll
    for (int vt = 0; vt < 4; vt++) o[vt] = {0.f, 0.f, 0.f, 0.f};
    float lsum[4] = {0.f, 0.f, 0.f, 0.f};

    const int ow = 48 - 16 * w;
    const int srcbase = lane & 48;
    const bf16x8 zero8 = {};

    int j0 = 0;
    for (int t = 0; t < steps; ++t, j0 += 32) {
        // QK^T: K fragments direct from global (j <= i0+31 always in-bounds)
        f32x4 s[2];
#pragma unroll
        for (int ct = 0; ct < 2; ct++) {
            s[ct] = {0.f, 0.f, 0.f, 0.f};
#pragma unroll
            for (int ks = 0; ks < 2; ks++) {
                bf16x8 bk = *(const bf16x8*)&kb[(size_t)(j0 + 16 * ct + m) * SS + ks * 32 + qd * 8];
                s[ct] = __builtin_amdgcn_mfma_f32_16x16x32_bf16(aq[ks], bk, s[ct], 0, 0, 0);
            }
        }
        // Q x Er: fragments direct from global, OOB rows (l > 1023) zeroed
        f32x4 r[3];
#pragma unroll
        for (int rt = 0; rt < 3; rt++) {
            const int l  = l0 + j0 + ow + 16 * rt + m;   // absolute Er row
            const bool okE = (l <= 1023);
            const int la = okE ? l : 1023;
            r[rt] = {0.f, 0.f, 0.f, 0.f};
#pragma unroll
            for (int ks = 0; ks < 2; ks++) {
                bf16x8 be = *(const bf16x8*)&eb[(size_t)la * SS + ks * 32 + qd * 8];
                be = okE ? be : zero8;
                r[rt] = __builtin_amdgcn_mfma_f32_16x16x32_bf16(aq[ks], be, r[rt], 0, 0, 0);
            }
        }

        // skew-diagonal extract + softmax numerator (R0 verbatim)
#pragma unroll
        for (int reg = 0; reg < 4; reg++) {
            const int r_ = qd * 4 + reg;
            const int i_ = i0 + 16 * w + r_;
            const int base = 15 - r_ + m;
            const int src  = srcbase | (base & 15);
            const float c0 = __shfl(r[0][reg], src);
            const float c1 = __shfl(r[1][reg], src);
            const float c2 = __shfl(r[2][reg], src);
            const float e0 = (base < 16) ? c0 : c1;
            const float e1 = (base < 16) ? c1 : c2;
            const float v0 = s[0][reg] + e0;
            const float v1 = s[1][reg] + e1;
            const float p0 = (j0 + m      > i_) ? 0.f : __expf(v0);
            const float p1 = (j0 + m + 16 > i_) ? 0.f : __expf(v1);
            lsum[reg] += p0 + p1;
            Ps[w][r_][m]      = f2b(p0);
            Ps[w][r_][m + 16] = f2b(p1);
        }

        // PV: P from wave-private LDS, V fragments direct from vT[d][t]
        bf16x8 pa = *(const bf16x8*)&Ps[w][m][qd * 8];
#pragma unroll
        for (int vt = 0; vt < 4; vt++) {
            bf16x8 bv = *(const bf16x8*)&vb[(size_t)(16 * vt + m) * TT + j0 + qd * 8];
            o[vt] = __builtin_amdgcn_mfma_f32_16x16x32_bf16(pa, bv, o[vt], 0, 0, 0);
        }
        // no barrier: waves are fully independent
    }

    // epilogue: direct write, wave owns its 16 output rows
#pragma unroll
    for (int reg = 0; reg < 4; reg++) {
        float l = lsum[reg];
#pragma unroll
        for (int off = 1; off < 16; off <<= 1) l += __shfl_xor(l, off);
        const int r_ = qd * 4 + reg;
        const int i_ = i0 + 16 * w + r_;
        const bool pad = (mask[bb * TT + i_] == 0);
        const float inv = 1.0f / l;
        const size_t rowbase = ((size_t)bb * TT + hh * 64 + (i_ >> 4)) * EE + (i_ & 15) * 64;
#pragma unroll
        for (int vt = 0; vt < 4; vt++) {
            const int d_ = 16 * vt + m;
            float val = pad ? vmean[bh * SS + d_] * (1.0f / 1024.0f)
                            : o[vt][reg] * inv;
            attn[rowbase + d_] = f2b(val);
        }
    }
}

// ---------------------------------------------------------------------------
// Kernel 4: MFMA bf16 GEMM  out = M @ Wo16^T + bo  (unchanged)
// ---------------------------------------------------------------------------
__global__ __launch_bounds__(256) void outproj_kernel(
    const ushort_t* __restrict__ A, const ushort_t* __restrict__ Wo,
    const float* __restrict__ bo, float* __restrict__ out)
{
    __shared__ __align__(16) ushort_t As[128][36];
    __shared__ __align__(16) ushort_t Bs[128][36];

    const int tid  = threadIdx.x;
    const int lane = tid & 63;
    const int w    = tid >> 6;
    const int m    = lane & 15;
    const int qd   = lane >> 4;
    const int wrow = (w & 1) * 64;
    const int wcol = (w >> 1) * 64;
    const int o0   = blockIdx.x * 128;
    const int n0   = blockIdx.y * 128;

    f32x4 acc[4][4];
#pragma unroll
    for (int rt = 0; rt < 4; rt++)
#pragma unroll
        for (int ct = 0; ct < 4; ct++) acc[rt][ct] = {0.f, 0.f, 0.f, 0.f};

    for (int k0 = 0; k0 < 1024; k0 += 32) {
        __syncthreads();
#pragma unroll
        for (int l = 0; l < 2; l++) {
            const int idx = tid + 256 * l;
            const int row = idx >> 2;
            const int sub = idx & 3;
            *(uint4*)&As[row][sub * 8] =
                *(const uint4*)&A[(size_t)(n0 + row) * 1024 + k0 + sub * 8];
            *(uint4*)&Bs[row][sub * 8] =
                *(const uint4*)&Wo[(size_t)(o0 + row) * 1024 + k0 + sub * 8];
        }
        __syncthreads();

        bf16x8 af[4], bf[4];
#pragma unroll
        for (int rt = 0; rt < 4; rt++)
            af[rt] = *(const bf16x8*)&As[wrow + rt * 16 + m][qd * 8];
#pragma unroll
        for (int ct = 0; ct < 4; ct++)
            bf[ct] = *(const bf16x8*)&Bs[wcol + ct * 16 + m][qd * 8];
#pragma unroll
        for (int rt = 0; rt < 4; rt++)
#pragma unroll
            for (int ct = 0; ct < 4; ct++)
                acc[rt][ct] = __builtin_amdgcn_mfma_f32_16x16x32_bf16(
                    af[rt], bf[ct], acc[rt][ct], 0, 0, 0);
    }

#pragma unroll
    for (int rt = 0; rt < 4; rt++) {
#pragma unroll
        for (int ct = 0; ct < 4; ct++) {
            const int oc = o0 + wcol + ct * 16 + m;
            const float bias = bo[oc];
#pragma unroll
            for (int reg = 0; reg < 4; reg++) {
                const int n = n0 + wrow + rt * 16 + qd * 4 + reg;
                out[(size_t)n * EE + oc] = acc[rt][ct][reg] + bias;
            }
        }
    }
}

// ---------------------------------------------------------------------------
// Launcher.  ws (ushort): q16|k16|vT16 (4M each) | er16 (1M) | wo16 (1M)
//            | M16 (4M) | vmean f32 (4096)
// ---------------------------------------------------------------------------
extern "C" void kernel_launch(void* const* d_in, const int* in_sizes, int n_in,
                              void* d_out, int out_size, void* d_ws, size_t ws_size,
                              hipStream_t stream)
{
    const float* x    = (const float*)d_in[0];
    const int*   mask = (const int*)d_in[1];
    const float* Wq   = (const float*)d_in[2];
    const float* Wk   = (const float*)d_in[3];
    const float* Wv   = (const float*)d_in[4];
    const float* Er   = (const float*)d_in[5];
    const float* Wo   = (const float*)d_in[6];
    const float* bo   = (const float*)d_in[7];
    float* out = (float*)d_out;

    const size_t QKV = (size_t)BB * HH * TT * SS;
    const int    nEr = HH * TT * SS;
    const int    nWo = EE * EE;
    ushort_t* q16   = (ushort_t*)d_ws;
    ushort_t* k16   = q16 + QKV;
    ushort_t* vT16  = k16 + QKV;
    ushort_t* er16  = vT16 + QKV;
    ushort_t* wo16  = er16 + nEr;
    ushort_t* M16   = wo16 + nWo;
    float*    vmean = (float*)(M16 + QKV);

    hipMemsetAsync(vmean, 0, BB * HH * SS * sizeof(float), stream);
    cvt2_kernel<<<dim3((nEr + nWo) / 1024), 256, 0, stream>>>(Er, er16, nEr, Wo, wo16, nWo);
    qkv_kernel<<<dim3(BB * TT / 128, HH), 256, 0, stream>>>(x, Wq, Wk, Wv, q16, k16, vT16, vmean);
    attn_kernel<<<dim3(BB * HH, TT / 64), 256, 0, stream>>>(q16, k16, vT16, er16, mask, vmean, M16);
    outproj_kernel<<<dim3(EE / 128, BB * TT / 128), 256, 0, stream>>>(M16, wo16, bo, out);
}

// Round 6
// 208.003 us; speedup vs baseline: 1.3522x; 1.3522x over previous
//
#include <hip/hip_runtime.h>
#include <hip/hip_bf16.h>
#include <math.h>
#include <stdint.h>

#define BB 4
#define TT 1024
#define EE 1024
#define HH 16
#define SS 64

typedef unsigned short ushort_t;
typedef __attribute__((ext_vector_type(8))) short bf16x8;
typedef __attribute__((ext_vector_type(8))) unsigned short u16x8;
typedef __attribute__((ext_vector_type(4))) unsigned short u16x4;
typedef __attribute__((ext_vector_type(4))) float f32x4;

__device__ __forceinline__ float b2f(ushort_t u) {
    union { float f; uint32_t i; } c;
    c.i = ((uint32_t)u) << 16;
    return c.f;
}
__device__ __forceinline__ ushort_t f2b(float f) {
    __hip_bfloat16 h = __float2bfloat16(f);
    return *(ushort_t*)&h;
}

// ---------------------------------------------------------------------------
// Kernel 0: fused fp32 -> bf16 converter (Er then Wo) + vmean zeroing
// (folds the hipMemsetAsync dispatch into block 0).
// ---------------------------------------------------------------------------
__global__ __launch_bounds__(256) void cvt2_kernel(
    const float* __restrict__ a, ushort_t* __restrict__ da, int na,
    const float* __restrict__ b, ushort_t* __restrict__ db, int nb,
    float* __restrict__ vmean)
{
    if (blockIdx.x == 0) {
        const float4 zz = {0.f, 0.f, 0.f, 0.f};
#pragma unroll
        for (int z = 0; z < 4; z++)
            ((float4*)vmean)[threadIdx.x * 4 + z] = zz;   // 4096 floats total
    }
    const int i4 = (blockIdx.x * 256 + threadIdx.x) * 4;
    if (i4 < na) {
        const float4 xv = *(const float4*)&a[i4];
        u16x4 o4 = { f2b(xv.x), f2b(xv.y), f2b(xv.z), f2b(xv.w) };
        *(u16x4*)&da[i4] = o4;
    } else {
        const int j4 = i4 - na;
        if (j4 < nb) {
            const float4 xv = *(const float4*)&b[j4];
            u16x4 o4 = { f2b(xv.x), f2b(xv.y), f2b(xv.z), f2b(xv.w) };
            *(u16x4*)&db[j4] = o4;
        }
    }
}

// ---------------------------------------------------------------------------
// Kernel 1: MFMA q/k/v projection + fused vmean accumulation. (R0 verbatim)
// ---------------------------------------------------------------------------
__global__ __launch_bounds__(256) void qkv_kernel(
    const float* __restrict__ x, const float* __restrict__ Wq,
    const float* __restrict__ Wk, const float* __restrict__ Wv,
    ushort_t* __restrict__ q, ushort_t* __restrict__ k, ushort_t* __restrict__ v,
    float* __restrict__ vmean)
{
    __shared__ __align__(16) ushort_t Xs[128][72];
    __shared__ __align__(16) ushort_t Wl[3][64][72];

    const int tid  = threadIdx.x;
    const int lane = tid & 63;
    const int w    = tid >> 6;
    const int m    = lane & 15;
    const int qd   = lane >> 4;
    const int n0   = blockIdx.x * 128;
    const int hh   = blockIdx.y;
    const int bb   = n0 >> 10;

#pragma unroll
    for (int l = 0; l < 8; l++) {
        const int idx = tid + 256 * l;
        const int row = idx >> 4;
        const int c4  = idx & 15;
        const float4 xv = *(const float4*)&x[(size_t)(n0 + row) * 1024 + hh * 64 + c4 * 4];
        u16x4 o4 = { f2b(xv.x), f2b(xv.y), f2b(xv.z), f2b(xv.w) };
        *(u16x4*)&Xs[row][c4 * 4] = o4;
    }
#pragma unroll
    for (int l = 0; l < 12; l++) {
        const int idx = tid + 256 * l;
        const int mo  = idx >> 10;
        const int r   = (idx >> 4) & 63;
        const int c4  = idx & 15;
        const float* W = (mo == 0) ? Wq : (mo == 1) ? Wk : Wv;
        const float4 wv = *(const float4*)&W[r * 64 + c4 * 4];
        u16x4 o4 = { f2b(wv.x), f2b(wv.y), f2b(wv.z), f2b(wv.w) };
        *(u16x4*)&Wl[mo][r][c4 * 4] = o4;
    }
    __syncthreads();

    f32x4 acc[2][3][4];
#pragma unroll
    for (int rt = 0; rt < 2; rt++)
#pragma unroll
        for (int mo = 0; mo < 3; mo++)
#pragma unroll
            for (int ct = 0; ct < 4; ct++) acc[rt][mo][ct] = {0.f, 0.f, 0.f, 0.f};

#pragma unroll
    for (int ks = 0; ks < 2; ks++) {
        bf16x8 af[2];
#pragma unroll
        for (int rt = 0; rt < 2; rt++)
            af[rt] = *(const bf16x8*)&Xs[32 * w + 16 * rt + m][ks * 32 + qd * 8];
#pragma unroll
        for (int mo = 0; mo < 3; mo++)
#pragma unroll
            for (int ct = 0; ct < 4; ct++) {
                bf16x8 bw = *(const bf16x8*)&Wl[mo][ct * 16 + m][ks * 32 + qd * 8];
#pragma unroll
                for (int rt = 0; rt < 2; rt++)
                    acc[rt][mo][ct] = __builtin_amdgcn_mfma_f32_16x16x32_bf16(
                        af[rt], bw, acc[rt][mo][ct], 0, 0, 0);
            }
    }

    const size_t obase = ((size_t)bb * HH + hh) * TT;
#pragma unroll
    for (int mo = 0; mo < 3; mo++) {
        ushort_t* dst = (mo == 0) ? q : (mo == 1) ? k : v;
        const float sc = (mo == 1) ? 0.03125f : 1.0f;
#pragma unroll
        for (int rt = 0; rt < 2; rt++)
#pragma unroll
            for (int reg = 0; reg < 4; reg++) {
                const int t = (n0 & 1023) + 32 * w + 16 * rt + qd * 4 + reg;
#pragma unroll
                for (int ct = 0; ct < 4; ct++)
                    dst[(obase + t) * SS + ct * 16 + m] = f2b(acc[rt][mo][ct][reg] * sc);
            }
    }

#pragma unroll
    for (int ct = 0; ct < 4; ct++) {
        float s = 0.f;
#pragma unroll
        for (int rt = 0; rt < 2; rt++)
#pragma unroll
            for (int reg = 0; reg < 4; reg++) s += acc[rt][2][ct][reg];
        s += __shfl_xor(s, 16);
        s += __shfl_xor(s, 32);
        if (qd == 0)
            atomicAdd(&vmean[(bb * HH + hh) * SS + ct * 16 + m], s);
    }
}

// ---------------------------------------------------------------------------
// Kernel 3: MFMA bf16 flash attention (verified R0 structure, 58.8us).
// ---------------------------------------------------------------------------
__global__ __launch_bounds__(256) void attn_kernel(
    const ushort_t* __restrict__ q, const ushort_t* __restrict__ k,
    const ushort_t* __restrict__ v, const ushort_t* __restrict__ er,
    const int* __restrict__ mask, const float* __restrict__ vmean,
    ushort_t* __restrict__ attn)
{
    __shared__ __align__(16) ushort_t Qs[64][72];
    __shared__ __align__(16) ushort_t Ks[32][72];
    __shared__ __align__(16) ushort_t Vt4[4][64][8];
    __shared__ __align__(16) ushort_t Es[96][72];
    __shared__ __align__(16) ushort_t Ps[4][16][40];

    const int tid  = threadIdx.x;
    const int lane = tid & 63;
    const int w    = tid >> 6;
    const int m    = lane & 15;
    const int qd   = lane >> 4;
    const int bh   = blockIdx.x;
    const int bb   = bh >> 4;
    const int hh   = bh & 15;
    const int i0   = blockIdx.y * 64;

    const ushort_t* qb = q + (size_t)bh * TT * SS;
    const ushort_t* kb = k + (size_t)bh * TT * SS;
    const ushort_t* vb = v + (size_t)bh * TT * SS;
    const ushort_t* eb = er + (size_t)hh * TT * SS;
    const int l0 = 960 - i0;

    for (int c = tid; c < 512; c += 256) {
        int row = c >> 3, sub = c & 7;
        *(uint4*)&Qs[row][sub * 8] = ((const uint4*)qb)[(size_t)(i0 + row) * 8 + sub];
    }
    for (int c = tid; c < 512; c += 256) {
        int row = c >> 3, sub = c & 7;
        int l = l0 + row;
        uint4 val = {0u, 0u, 0u, 0u};
        if (l <= 1023) val = ((const uint4*)eb)[(size_t)l * 8 + sub];
        *(uint4*)&Es[row][sub * 8] = val;
    }

    const int krow = tid >> 3, ksub = tid & 7;
    const int vd   = tid & 63, vjh = tid >> 6;
    uint4 kreg, ereg;
    u16x8 vreg;

    {
        kreg = ((const uint4*)kb)[(size_t)krow * 8 + ksub];
#pragma unroll
        for (int jj = 0; jj < 8; jj++)
            vreg[jj] = vb[(size_t)(vjh * 8 + jj) * SS + vd];
        const int l = l0 + 64 + krow;
        ereg = (uint4){0u, 0u, 0u, 0u};
        if (l <= 1023) ereg = ((const uint4*)eb)[(size_t)l * 8 + ksub];
    }
    __syncthreads();

    bf16x8 aq[2];
#pragma unroll
    for (int ks = 0; ks < 2; ks++)
        aq[ks] = *(const bf16x8*)&Qs[16 * w + m][ks * 32 + qd * 8];

    f32x4 o[4];
#pragma unroll
    for (int vt = 0; vt < 4; vt++) o[vt] = {0.f, 0.f, 0.f, 0.f};
    float lsum[4] = {0.f, 0.f, 0.f, 0.f};

    const int ow = 48 - 16 * w;
    const int srcbase = lane & 48;

    for (int j0 = 0; j0 <= i0 + 32; j0 += 32) {
        *(uint4*)&Ks[krow][ksub * 8] = kreg;
        *(u16x8*)&Vt4[vjh][vd][0] = vreg;
        {
            const int slot = (64 + j0) % 96 + krow;
            *(uint4*)&Es[slot][ksub * 8] = ereg;
        }
        __syncthreads();

        if (j0 <= i0) {
            const int jn = j0 + 32;
            kreg = ((const uint4*)kb)[(size_t)(jn + krow) * 8 + ksub];
#pragma unroll
            for (int jj = 0; jj < 8; jj++)
                vreg[jj] = vb[(size_t)(jn + vjh * 8 + jj) * SS + vd];
            const int l = l0 + 64 + jn + krow;
            ereg = (uint4){0u, 0u, 0u, 0u};
            if (l <= 1023) ereg = ((const uint4*)eb)[(size_t)l * 8 + ksub];
        }

        f32x4 s[2];
#pragma unroll
        for (int ct = 0; ct < 2; ct++) {
            s[ct] = {0.f, 0.f, 0.f, 0.f};
#pragma unroll
            for (int ks = 0; ks < 2; ks++) {
                bf16x8 bk = *(const bf16x8*)&Ks[16 * ct + m][ks * 32 + qd * 8];
                s[ct] = __builtin_amdgcn_mfma_f32_16x16x32_bf16(aq[ks], bk, s[ct], 0, 0, 0);
            }
        }
        f32x4 r[3];
#pragma unroll
        for (int rt = 0; rt < 3; rt++) {
            const int row0 = (ow + 16 * rt + j0) % 96;
            r[rt] = {0.f, 0.f, 0.f, 0.f};
#pragma unroll
            for (int ks = 0; ks < 2; ks++) {
                bf16x8 be = *(const bf16x8*)&Es[row0 + m][ks * 32 + qd * 8];
                r[rt] = __builtin_amdgcn_mfma_f32_16x16x32_bf16(aq[ks], be, r[rt], 0, 0, 0);
            }
        }

#pragma unroll
        for (int reg = 0; reg < 4; reg++) {
            const int r_ = qd * 4 + reg;
            const int i_ = i0 + 16 * w + r_;
            const int base = 15 - r_ + m;
            const int src  = srcbase | (base & 15);
            const float c0 = __shfl(r[0][reg], src);
            const float c1 = __shfl(r[1][reg], src);
            const float c2 = __shfl(r[2][reg], src);
            const float e0 = (base < 16) ? c0 : c1;
            const float e1 = (base < 16) ? c1 : c2;
            const float v0 = s[0][reg] + e0;
            const float v1 = s[1][reg] + e1;
            const float p0 = (j0 + m      > i_) ? 0.f : __expf(v0);
            const float p1 = (j0 + m + 16 > i_) ? 0.f : __expf(v1);
            lsum[reg] += p0 + p1;
            Ps[w][r_][m]      = f2b(p0);
            Ps[w][r_][m + 16] = f2b(p1);
        }

        bf16x8 pa = *(const bf16x8*)&Ps[w][m][qd * 8];
#pragma unroll
        for (int vt = 0; vt < 4; vt++) {
            bf16x8 bv = *(const bf16x8*)&Vt4[qd][16 * vt + m][0];
            o[vt] = __builtin_amdgcn_mfma_f32_16x16x32_bf16(pa, bv, o[vt], 0, 0, 0);
        }
        __syncthreads();
    }

#pragma unroll
    for (int reg = 0; reg < 4; reg++) {
        float l = lsum[reg];
#pragma unroll
        for (int off = 1; off < 16; off <<= 1) l += __shfl_xor(l, off);
        const int r_ = qd * 4 + reg;
        const int i_ = i0 + 16 * w + r_;
        const bool pad = (mask[bb * TT + i_] == 0);
        const float inv = 1.0f / l;
        const size_t rowbase = ((size_t)bb * TT + hh * 64 + (i_ >> 4)) * EE + (i_ & 15) * 64;
#pragma unroll
        for (int vt = 0; vt < 4; vt++) {
            const int d_ = 16 * vt + m;
            float val = pad ? vmean[bh * SS + d_] * (1.0f / 1024.0f)
                            : o[vt][reg] * inv;
            attn[rowbase + d_] = f2b(val);
        }
    }
}

// ---------------------------------------------------------------------------
// Kernel 4: MFMA bf16 GEMM  out = M @ Wo16^T + bo.
// R6 rewrite: BM=128, BN=64, BK=64 -> grid (16,32)=512 blocks (2/CU, real
// inter-block overlap vs old 1/CU); register-prefetch double buffer: next
// K-tile's global loads are issued BEFORE the compute phase so L2/HBM
// latency hides under the 16 MFMAs x 4 waves.  Padded [72] LDS rows keep
// the verified 2-way-max bank pattern; C-write mapping unchanged.
// ---------------------------------------------------------------------------
__global__ __launch_bounds__(256) void outproj_kernel(
    const ushort_t* __restrict__ A, const ushort_t* __restrict__ Wo,
    const float* __restrict__ bo, float* __restrict__ out)
{
    __shared__ __align__(16) ushort_t As[128][72];
    __shared__ __align__(16) ushort_t Bs[64][72];

    const int tid  = threadIdx.x;
    const int lane = tid & 63;
    const int w    = tid >> 6;          // 0..3: 32-row M-slice per wave
    const int m    = lane & 15;
    const int qd   = lane >> 4;
    const int o0   = blockIdx.x * 64;
    const int n0   = blockIdx.y * 128;

    const int srow = tid >> 3;          // staging row (A: +0/+32/+64/+96)
    const int ssub = tid & 7;           // 16B sub-chunk

    uint4 pa[4], pb[2];
    // prologue: load K-tile 0 into registers
#pragma unroll
    for (int l = 0; l < 4; l++)
        pa[l] = *(const uint4*)&A[(size_t)(n0 + srow + 32 * l) * 1024 + ssub * 8];
#pragma unroll
    for (int l = 0; l < 2; l++)
        pb[l] = *(const uint4*)&Wo[(size_t)(o0 + srow + 32 * l) * 1024 + ssub * 8];

    f32x4 acc[2][4];
#pragma unroll
    for (int rt = 0; rt < 2; rt++)
#pragma unroll
        for (int ct = 0; ct < 4; ct++) acc[rt][ct] = {0.f, 0.f, 0.f, 0.f};

    for (int k0 = 0; k0 < 1024; k0 += 64) {
        __syncthreads();                 // prev compute done reading LDS
#pragma unroll
        for (int l = 0; l < 4; l++)
            *(uint4*)&As[srow + 32 * l][ssub * 8] = pa[l];
#pragma unroll
        for (int l = 0; l < 2; l++)
            *(uint4*)&Bs[srow + 32 * l][ssub * 8] = pb[l];
        __syncthreads();

        if (k0 + 64 < 1024) {            // issue next tile's loads early
            const int kn = k0 + 64;
#pragma unroll
            for (int l = 0; l < 4; l++)
                pa[l] = *(const uint4*)&A[(size_t)(n0 + srow + 32 * l) * 1024 + kn + ssub * 8];
#pragma unroll
            for (int l = 0; l < 2; l++)
                pb[l] = *(const uint4*)&Wo[(size_t)(o0 + srow + 32 * l) * 1024 + kn + ssub * 8];
        }

#pragma unroll
        for (int ks = 0; ks < 2; ks++) {
            bf16x8 af[2], bf[4];
#pragma unroll
            for (int rt = 0; rt < 2; rt++)
                af[rt] = *(const bf16x8*)&As[32 * w + rt * 16 + m][ks * 32 + qd * 8];
#pragma unroll
            for (int ct = 0; ct < 4; ct++)
                bf[ct] = *(const bf16x8*)&Bs[ct * 16 + m][ks * 32 + qd * 8];
#pragma unroll
            for (int rt = 0; rt < 2; rt++)
#pragma unroll
                for (int ct = 0; ct < 4; ct++)
                    acc[rt][ct] = __builtin_amdgcn_mfma_f32_16x16x32_bf16(
                        af[rt], bf[ct], acc[rt][ct], 0, 0, 0);
        }
    }

#pragma unroll
    for (int rt = 0; rt < 2; rt++) {
#pragma unroll
        for (int ct = 0; ct < 4; ct++) {
            const int oc = o0 + ct * 16 + m;
            const float bias = bo[oc];
#pragma unroll
            for (int reg = 0; reg < 4; reg++) {
                const int n = n0 + 32 * w + rt * 16 + qd * 4 + reg;
                out[(size_t)n * EE + oc] = acc[rt][ct][reg] + bias;
            }
        }
    }
}

// ---------------------------------------------------------------------------
// Launcher.  ws (ushort): q16|k16|v16 (4M each) | er16 (1M) | wo16 (1M)
//            | M16 (4M) | vmean f32 (4096)
// ---------------------------------------------------------------------------
extern "C" void kernel_launch(void* const* d_in, const int* in_sizes, int n_in,
                              void* d_out, int out_size, void* d_ws, size_t ws_size,
                              hipStream_t stream)
{
    const float* x    = (const float*)d_in[0];
    const int*   mask = (const int*)d_in[1];
    const float* Wq   = (const float*)d_in[2];
    const float* Wk   = (const float*)d_in[3];
    const float* Wv   = (const float*)d_in[4];
    const float* Er   = (const float*)d_in[5];
    const float* Wo   = (const float*)d_in[6];
    const float* bo   = (const float*)d_in[7];
    float* out = (float*)d_out;

    const size_t QKV = (size_t)BB * HH * TT * SS;
    const int    nEr = HH * TT * SS;
    const int    nWo = EE * EE;
    ushort_t* q16   = (ushort_t*)d_ws;
    ushort_t* k16   = q16 + QKV;
    ushort_t* v16   = k16 + QKV;
    ushort_t* er16  = v16 + QKV;
    ushort_t* wo16  = er16 + nEr;
    ushort_t* M16   = wo16 + nWo;
    float*    vmean = (float*)(M16 + QKV);

    cvt2_kernel<<<dim3((nEr + nWo) / 1024), 256, 0, stream>>>(Er, er16, nEr, Wo, wo16, nWo, vmean);
    qkv_kernel<<<dim3(BB * TT / 128, HH), 256, 0, stream>>>(x, Wq, Wk, Wv, q16, k16, v16, vmean);
    attn_kernel<<<dim3(BB * HH, TT / 64), 256, 0, stream>>>(q16, k16, v16, er16, mask, vmean, M16);
    outproj_kernel<<<dim3(EE / 64, BB * TT / 128), 256, 0, stream>>>(M16, wo16, bo, out);
}